// Round 3
// baseline (1665.160 us; speedup 1.0000x reference)
//
#include <hip/hip_runtime.h>
#include <math.h>

// Problem constants
#define ST 64      // sequence length T
#define NBAT 64    // batch B
#define ED 256     // embedding dim E
#define HD 512     // hidden dim H
#define G4 2048    // 4*H
#define VO 32000   // vocab
#define LSTM_BLOCKS 64

typedef unsigned int u32;
typedef unsigned long long u64;
typedef unsigned short u16;
typedef __bf16 bf16;
typedef bf16 bf16x8 __attribute__((ext_vector_type(8)));
typedef float f32x4 __attribute__((ext_vector_type(4)));

__device__ __forceinline__ float sigm(float x) { return 1.f / (1.f + expf(-x)); }

// ---------------- prep kernels ----------------

__global__ void k_lengths(const int* __restrict__ toks, int* __restrict__ len) {
  int b = threadIdx.x;
  if (b < NBAT) {
    int n = 0;
    for (int t = 0; t < ST; ++t) n += (toks[b * ST + t] != 0) ? 1 : 0;
    len[b] = n;
  }
}

__global__ void k_cast(const float* __restrict__ src, bf16* __restrict__ dst, int n) {
  int i = blockIdx.x * blockDim.x + threadIdx.x;
  if (i < n) dst[i] = (bf16)src[i];
}

__global__ void k_bias(const float* __restrict__ a, const float* __restrict__ b,
                       float* __restrict__ o) {
  int i = blockIdx.x * blockDim.x + threadIdx.x;
  if (i < G4) o[i] = a[i] + b[i];
}

// encX[t][b][e] = emb[toks[b][t]][e]; decX[t][b][e] = emb[t==0 ? 1 : toks[b][t-1]][e]
__global__ void k_gather(const int* __restrict__ toks, const float* __restrict__ emb,
                         bf16* __restrict__ encX, bf16* __restrict__ decX) {
  int i = blockIdx.x * blockDim.x + threadIdx.x;
  if (i >= ST * NBAT * ED) return;
  int e = i % ED;
  int tb = i / ED;
  int b = tb % NBAT;
  int t = tb / NBAT;
  int te = toks[b * ST + t];
  encX[i] = (bf16)emb[te * ED + e];
  int td = (t == 0) ? 1 : toks[b * ST + t - 1];
  decX[i] = (bf16)emb[td * ED + e];
}

// ---------------- persistent LSTM kernel ----------------
//
// Fence-free h-exchange: h values AND flags both travel through the
// cache-bypassing agent-scope atomic path (the coherence point past the
// non-coherent per-XCD L2s). No release/acquire fences -> no buffer_wbl2 /
// buffer_inv in the step loop (those were ~8 us/step in rounds 1-2).
//
//   fire(v):  __syncthreads() (each wave drains vmcnt(0) -> all atomic
//             h-stores acked at the coherence point), then tid0 does a
//             RELAXED atomic store flags[myblock]=v.
//   wait(v):  wave 0: 64 lanes RELAXED-load the 64 flags until
//             __all(flag >= v); __syncthreads. h-loads after the barrier
//             are atomic (cache-bypassing) -> fresh by construction.
// Double-buffer safety: flag=t+1 fires after this block's step-t h-loads
// completed (vmcnt drained at the same barrier), so all-flags>=t+2 implies
// nobody still reads the buffer step t+2 overwrites.

// Grid: 64 blocks x 512 threads. Block bk owns hidden units u0..u0+7 (u0=8*bk)
// for all 4 gates -> 32 gate columns. Gates tile per step: [64 batch x 32 cols],
// K = 512 (h) + 256 (x). 8 waves: wave w -> m-frag (w&3), n-frag (w>>2).
// Gate col order in the 32: [i*8 | f*8 | g*8 | o*8].
__global__ __launch_bounds__(512, 2) void k_lstm(
    const bf16* __restrict__ encX, const bf16* __restrict__ decX,
    const bf16* __restrict__ WihE, const bf16* __restrict__ WhhE,
    const bf16* __restrict__ WihD, const bf16* __restrict__ WhhD,
    const float* __restrict__ bsumE, const float* __restrict__ bsumD,
    const int* __restrict__ len,
    u32* __restrict__ hbuf32,  // [2][NBAT][HD/2] double-buffered h (u32-packed bf16 pairs)
    u32* __restrict__ hs32,    // [ST][NBAT][HD/2] decoder outputs (same packing)
    u32* flags)                // [64] per-block progress, 16B-spaced
{
  // +8 pad per row: stride 1040B/528B -> bank offset 4/row -> 2-way max (free)
  __shared__ __align__(16) bf16 Wr[32][HD + 8];
  __shared__ __align__(16) bf16 Wx[32][ED + 8];
  __shared__ float gl[64][33];

  const int tid  = threadIdx.x;
  const int lane = tid & 63;
  const int wid  = tid >> 6;
  const int wm   = wid & 3;        // m-fragment (batch rows 16*wm..)
  const int wn   = wid >> 2;       // n-fragment (cols 16*wn..), 0..1
  const int u0   = blockIdx.x * 8;
  const int r16  = lane & 15;
  const int kc   = (lane >> 4) * 8;
  const int arow = 16 * wm + r16;  // batch row for A-frags
  const int brow = 16 * wn + r16;  // LDS row for B-frags

  // epilogue mapping: 256 threads, one (batch, unit-pair) per thread
  const int eb   = (tid & 255) >> 2;   // 0..63
  const int j2   = (tid & 3) * 2;      // unit pair base within the 8 owned units
  const int elen = len[eb];
  const int hidx32 = eb * (HD / 2) + (u0 >> 1) + (tid & 3);

  u32 hp = 0;  // this thread's packed h pair; carries z across the phase switch

  for (int phase = 0; phase < 2; ++phase) {
    const bf16* Wih  = phase ? WihD : WihE;
    const bf16* Whh  = phase ? WhhD : WhhE;
    const float* bsum = phase ? bsumD : bsumE;
    const bf16* Xall = phase ? decX : encX;

    // load this block's weight slices into LDS (rows: gate q = n>>3, unit u0+(n&7))
    for (int idx = tid; idx < 32 * HD; idx += 512) {
      int n = idx >> 9, k = idx & (HD - 1);
      Wr[n][k] = Whh[((n >> 3) * HD + u0 + (n & 7)) * HD + k];
    }
    for (int idx = tid; idx < 32 * ED; idx += 512) {
      int n = idx >> 8, k = idx & (ED - 1);
      Wx[n][k] = Wih[((n >> 3) * HD + u0 + (n & 7)) * ED + k];
    }
    const float bi0 = bsum[0 * HD + u0 + j2], bi1 = bsum[0 * HD + u0 + j2 + 1];
    const float bf0 = bsum[1 * HD + u0 + j2], bf1 = bsum[1 * HD + u0 + j2 + 1];
    const float bg0 = bsum[2 * HD + u0 + j2], bg1 = bsum[2 * HD + u0 + j2 + 1];
    const float bo0 = bsum[3 * HD + u0 + j2], bo1 = bsum[3 * HD + u0 + j2 + 1];
    float c0 = 0.f, c1 = 0.f;
    __syncthreads();

    for (int t = 0; t < ST; ++t) {
      const int step = phase * ST + t;
      const u32* hin32 = hbuf32 + (step & 1) * (NBAT * HD / 2);
      u32* hout32      = hbuf32 + ((step & 1) ^ 1) * (NBAT * HD / 2);
      const bf16* xin = Xall + t * (NBAT * ED);

      // ---- x-part first: independent of h, overlaps flag propagation ----
      f32x4 acc1 = {0.f, 0.f, 0.f, 0.f};
      #pragma unroll
      for (int kk = 0; kk < ED / 32; ++kk) {
        bf16x8 av = *(const bf16x8*)(xin + arow * ED + kk * 32 + kc);
        bf16x8 bv = *(const bf16x8*)(&Wx[brow][kk * 32 + kc]);
        acc1 = __builtin_amdgcn_mfma_f32_16x16x32_bf16(av, bv, acc1, 0, 0, 0);
      }

      // ---- wait for all blocks to have produced h(step) ----
      if (step > 0) {
        if (wid == 0) {
          u32 v = __hip_atomic_load(&flags[lane * 4], __ATOMIC_RELAXED,
                                    __HIP_MEMORY_SCOPE_AGENT);
          while (!__all((int)(v >= (u32)step))) {
            __builtin_amdgcn_s_sleep(1);
            v = __hip_atomic_load(&flags[lane * 4], __ATOMIC_RELAXED,
                                  __HIP_MEMORY_SCOPE_AGENT);
          }
        }
        __syncthreads();
      }

      // ---- h-part: gates += h(step) @ Whh^T (cache-bypassing atomic loads) ----
      f32x4 acc0 = {0.f, 0.f, 0.f, 0.f};
      #pragma unroll
      for (int kk = 0; kk < HD / 32; ++kk) {
        const u64* hq = (const u64*)(hin32 + arow * (HD / 2) + kk * 16 + (kc >> 1));
        u64 q0 = __hip_atomic_load(hq,     __ATOMIC_RELAXED, __HIP_MEMORY_SCOPE_AGENT);
        u64 q1 = __hip_atomic_load(hq + 1, __ATOMIC_RELAXED, __HIP_MEMORY_SCOPE_AGENT);
        union { u64 q[2]; bf16x8 v; } cv;
        cv.q[0] = q0; cv.q[1] = q1;
        bf16x8 bv = *(const bf16x8*)(&Wr[brow][kk * 32 + kc]);
        acc0 = __builtin_amdgcn_mfma_f32_16x16x32_bf16(cv.v, bv, acc0, 0, 0, 0);
      }
      #pragma unroll
      for (int r = 0; r < 4; ++r)
        gl[16 * wm + (lane >> 4) * 4 + r][16 * wn + r16] = acc0[r] + acc1[r];
      __syncthreads();

      // elementwise LSTM cell: 256 threads, two adjacent units each
      if (tid < 256) {
        float gi0 = gl[eb][j2]          + bi0, gi1 = gl[eb][j2 + 1]      + bi1;
        float gf0 = gl[eb][8 + j2]      + bf0, gf1 = gl[eb][9 + j2]      + bf1;
        float gg0 = gl[eb][16 + j2]     + bg0, gg1 = gl[eb][17 + j2]     + bg1;
        float go0 = gl[eb][24 + j2]     + bo0, go1 = gl[eb][25 + j2]     + bo1;
        bool upd = (phase == 1) || (t < elen);
        float cn0 = sigm(gf0) * c0 + sigm(gi0) * tanhf(gg0);
        float cn1 = sigm(gf1) * c1 + sigm(gi1) * tanhf(gg1);
        float hn0 = sigm(go0) * tanhf(cn0);
        float hn1 = sigm(go1) * tanhf(cn1);
        if (upd) {
          c0 = cn0; c1 = cn1;
          union { u32 u; bf16 h[2]; } pk;
          pk.h[0] = (bf16)hn0; pk.h[1] = (bf16)hn1;
          hp = pk.u;
        }
        __hip_atomic_store(&hout32[hidx32], hp, __ATOMIC_RELAXED,
                           __HIP_MEMORY_SCOPE_AGENT);
        if (phase == 1) hs32[t * (NBAT * HD / 2) + hidx32] = hp;
      }

      // ---- fire: publish h(step+1) (relaxed; barrier already drained stores) ----
      if (step < 2 * ST - 1) {
        __syncthreads();  // each wave: s_waitcnt vmcnt(0) before s_barrier
        if (tid == 0)
          __hip_atomic_store(&flags[blockIdx.x * 4], (u32)(step + 1),
                             __ATOMIC_RELAXED, __HIP_MEMORY_SCOPE_AGENT);
      }
    }
  }
}

// ---------------- output projection GEMM ----------------
// logits[b][t][v] = sum_h hs[t][b][h] * lin_W[v][h] + lin_b[v]
// M = ST*NBAT = 4096 (row m = t*64+b), N = VO = 32000, K = HD = 512.
// 128x128 tile, BK=64, 4 waves each owning a 64x64 quadrant (4x4 frags).
__global__ __launch_bounds__(256, 2) void k_logits(
    const bf16* __restrict__ hsb, const bf16* __restrict__ Wb,
    const float* __restrict__ linb, float* __restrict__ out)
{
  __shared__ __align__(16) bf16 As[128][72];  // +8 pad -> conflict-free frag reads
  __shared__ __align__(16) bf16 Bs[128][72];
  const int tid  = threadIdx.x;
  const int lane = tid & 63;
  const int wid  = tid >> 6;
  const int wm   = wid >> 1, wn = wid & 1;
  const int bn   = blockIdx.x * 128;
  const int bm   = blockIdx.y * 128;
  const int r16  = lane & 15, kh = lane >> 4;

  f32x4 acc[4][4];
  #pragma unroll
  for (int i = 0; i < 4; ++i)
    #pragma unroll
    for (int j = 0; j < 4; ++j) acc[i][j] = (f32x4){0.f, 0.f, 0.f, 0.f};

  const int srow = tid >> 3;        // 0..31
  const int scol = (tid & 7) * 8;   // 0..56

  for (int kt = 0; kt < HD / 64; ++kt) {
    __syncthreads();
    #pragma unroll
    for (int p = 0; p < 4; ++p) {
      int row = p * 32 + srow;
      *(bf16x8*)(&As[row][scol]) =
          *(const bf16x8*)(hsb + (size_t)(bm + row) * HD + kt * 64 + scol);
      *(bf16x8*)(&Bs[row][scol]) =
          *(const bf16x8*)(Wb + (size_t)(bn + row) * HD + kt * 64 + scol);
    }
    __syncthreads();
    #pragma unroll
    for (int kk = 0; kk < 2; ++kk) {
      bf16x8 af[4], bfv[4];
      #pragma unroll
      for (int i = 0; i < 4; ++i)
        af[i] = *(const bf16x8*)(&As[64 * wm + 16 * i + r16][kk * 32 + kh * 8]);
      #pragma unroll
      for (int j = 0; j < 4; ++j)
        bfv[j] = *(const bf16x8*)(&Bs[64 * wn + 16 * j + r16][kk * 32 + kh * 8]);
      #pragma unroll
      for (int i = 0; i < 4; ++i)
        #pragma unroll
        for (int j = 0; j < 4; ++j)
          acc[i][j] = __builtin_amdgcn_mfma_f32_16x16x32_bf16(af[i], bfv[j], acc[i][j], 0, 0, 0);
    }
  }

  #pragma unroll
  for (int j = 0; j < 4; ++j) {
    int ncol = bn + 64 * wn + 16 * j + r16;
    float bias = linb[ncol];
    #pragma unroll
    for (int i = 0; i < 4; ++i) {
      int mbase = bm + 64 * wm + 16 * i + kh * 4;
      #pragma unroll
      for (int r = 0; r < 4; ++r) {
        int m = mbase + r;
        int b = m & 63, t = m >> 6;
        out[(size_t)(b * ST + t) * VO + ncol] = acc[i][j][r] + bias;
      }
    }
  }
}

// ---------------- host ----------------

extern "C" void kernel_launch(void* const* d_in, const int* in_sizes, int n_in,
                              void* d_out, int out_size, void* d_ws, size_t ws_size,
                              hipStream_t stream) {
  const int*   toks = (const int*)d_in[0];
  const float* emb  = (const float*)d_in[1];
  const float* eWih = (const float*)d_in[2];
  const float* eWhh = (const float*)d_in[3];
  const float* ebih = (const float*)d_in[4];
  const float* ebhh = (const float*)d_in[5];
  const float* dWih = (const float*)d_in[6];
  const float* dWhh = (const float*)d_in[7];
  const float* dbih = (const float*)d_in[8];
  const float* dbhh = (const float*)d_in[9];
  const float* linW = (const float*)d_in[10];
  const float* linb = (const float*)d_in[11];
  float* out = (float*)d_out;

  char* ws = (char*)d_ws;
  size_t off = 0;
  auto alloc = [&](size_t bytes) {
    void* p = ws + off;
    off = (off + bytes + 255) & ~(size_t)255;
    return p;
  };
  bf16* encX  = (bf16*)alloc((size_t)ST * NBAT * ED * 2);
  bf16* decX  = (bf16*)alloc((size_t)ST * NBAT * ED * 2);
  bf16* WihEb = (bf16*)alloc((size_t)G4 * ED * 2);
  bf16* WhhEb = (bf16*)alloc((size_t)G4 * HD * 2);
  bf16* WihDb = (bf16*)alloc((size_t)G4 * ED * 2);
  bf16* WhhDb = (bf16*)alloc((size_t)G4 * HD * 2);
  bf16* WbL   = (bf16*)alloc((size_t)VO * HD * 2);
  float* bsumE = (float*)alloc(G4 * 4);
  float* bsumD = (float*)alloc(G4 * 4);
  u32*  hbuf  = (u32*)alloc((size_t)2 * NBAT * HD * 2);
  u32*  hs    = (u32*)alloc((size_t)ST * NBAT * HD * 2);
  int*  len   = (int*)alloc(NBAT * 4);
  u32*  flags = (u32*)alloc(1024);

  hipMemsetAsync(hbuf, 0, (size_t)2 * NBAT * HD * 2, stream);
  hipMemsetAsync(flags, 0, 1024, stream);

  k_lengths<<<1, 64, 0, stream>>>(toks, len);
  k_bias<<<(G4 + 255) / 256, 256, 0, stream>>>(ebih, ebhh, bsumE);
  k_bias<<<(G4 + 255) / 256, 256, 0, stream>>>(dbih, dbhh, bsumD);
  k_cast<<<(G4 * ED + 255) / 256, 256, 0, stream>>>(eWih, WihEb, G4 * ED);
  k_cast<<<(G4 * HD + 255) / 256, 256, 0, stream>>>(eWhh, WhhEb, G4 * HD);
  k_cast<<<(G4 * ED + 255) / 256, 256, 0, stream>>>(dWih, WihDb, G4 * ED);
  k_cast<<<(G4 * HD + 255) / 256, 256, 0, stream>>>(dWhh, WhhDb, G4 * HD);
  k_cast<<<(VO * HD + 255) / 256, 256, 0, stream>>>(linW, WbL, VO * HD);
  k_gather<<<(ST * NBAT * ED + 255) / 256, 256, 0, stream>>>(toks, emb, encX, decX);

  k_lstm<<<LSTM_BLOCKS, 512, 0, stream>>>(encX, decX, WihEb, WhhEb, WihDb, WhhDb,
                                          bsumE, bsumD, len, hbuf, hs, flags);

  k_logits<<<dim3(VO / 128, (ST * NBAT) / 128), 256, 0, stream>>>((const bf16*)hs, WbL, linb, out);
}

// Round 5
// 1266.245 us; speedup vs baseline: 1.3150x; 1.3150x over previous
//
#include <hip/hip_runtime.h>
#include <math.h>

// Problem constants
#define ST 64      // sequence length T
#define NBAT 64    // batch B
#define ED 256     // embedding dim E
#define HD 512     // hidden dim H
#define G4 2048    // 4*H
#define VO 32000   // vocab
#define LSTM_BLOCKS 64

typedef unsigned int u32;
typedef unsigned long long u64;
typedef unsigned short u16;
typedef __bf16 bf16;
typedef bf16 bf16x8 __attribute__((ext_vector_type(8)));
typedef float f32x4 __attribute__((ext_vector_type(4)));

__device__ __forceinline__ float sigm(float x) { return 1.f / (1.f + expf(-x)); }
__device__ __forceinline__ bf16x8 asbf8(f32x4 x) {
  union { f32x4 f; bf16x8 b; } u; u.f = x; return u.b;
}

// ---------------- prep kernels ----------------

__global__ void k_lengths(const int* __restrict__ toks, int* __restrict__ len) {
  int b = threadIdx.x;
  if (b < NBAT) {
    int n = 0;
    for (int t = 0; t < ST; ++t) n += (toks[b * ST + t] != 0) ? 1 : 0;
    len[b] = n;
  }
}

__global__ void k_cast(const float* __restrict__ src, bf16* __restrict__ dst, int n) {
  int i = blockIdx.x * blockDim.x + threadIdx.x;
  if (i < n) dst[i] = (bf16)src[i];
}

__global__ void k_bias(const float* __restrict__ a, const float* __restrict__ b,
                       float* __restrict__ o) {
  int i = blockIdx.x * blockDim.x + threadIdx.x;
  if (i < G4) o[i] = a[i] + b[i];
}

// encX[t][b][e] = emb[toks[b][t]][e]; decX[t][b][e] = emb[t==0 ? 1 : toks[b][t-1]][e]
__global__ void k_gather(const int* __restrict__ toks, const float* __restrict__ emb,
                         bf16* __restrict__ encX, bf16* __restrict__ decX) {
  int i = blockIdx.x * blockDim.x + threadIdx.x;
  if (i >= ST * NBAT * ED) return;
  int e = i % ED;
  int tb = i / ED;
  int b = tb % NBAT;
  int t = tb / NBAT;
  int te = toks[b * ST + t];
  encX[i] = (bf16)emb[te * ED + e];
  int td = (t == 0) ? 1 : toks[b * ST + t - 1];
  decX[i] = (bf16)emb[td * ED + e];
}

// ---------------- persistent LSTM kernel ----------------
//
// Sync protocol (fence-free; no buffer_inv / buffer_wbl2 in the loop):
//   fire(v):  __syncthreads() (each wave: s_waitcnt vmcnt(0) -> this block's
//             agent-scope h-stores acked at the coherence point), then tid0
//             RELAXED-stores flags[myblock]=v.
//   wait(v):  wave 0: 64 lanes RELAXED-load the 64 flags until __all(>=v);
//             __syncthreads.
//   h data:   producers store via relaxed agent atomics (bypass noncoherent
//             L2s); consumers load via ONE inline-asm cluster of 16
//             global_load_dwordx4 sc0 sc1 + single vmcnt(0) -> coherent AND
//             pipelined (round 3's per-atomic-load serialization was the
//             regression: ~16 serial fabric latencies per wave per step).
// Double-buffer safety: flag=t+1 fires after this block's step-t h-loads
// completed (vmcnt(0) inside the asm precedes the fire barrier), so
// all-flags>=t+2 implies nobody still reads the buffer step t+2 overwrites.
// Because NO invalidates run, x tiles / weights stay hot in L2.

// Grid: 64 blocks x 512 threads. Block bk owns hidden units u0..u0+7 (u0=8*bk)
// for all 4 gates -> 32 gate columns. Gates tile per step: [64 batch x 32 cols],
// K = 512 (h) + 256 (x). 8 waves: wave w -> m-frag (w&3), n-frag (w>>2).
// Gate col order in the 32: [i*8 | f*8 | g*8 | o*8].
__global__ __launch_bounds__(512, 2) void k_lstm(
    const bf16* __restrict__ encX, const bf16* __restrict__ decX,
    const bf16* __restrict__ WihE, const bf16* __restrict__ WhhE,
    const bf16* __restrict__ WihD, const bf16* __restrict__ WhhD,
    const float* __restrict__ bsumE, const float* __restrict__ bsumD,
    const int* __restrict__ len,
    u32* __restrict__ hbuf32,  // [2][NBAT][HD/2] double-buffered h (u32-packed bf16 pairs)
    u32* __restrict__ hs32,    // [ST][NBAT][HD/2] decoder outputs (same packing)
    u32* flags)                // [64] per-block progress, 16B-spaced
{
  // +8 pad per row: stride 1040B/528B (65/33 16B-units, odd) -> b128 reads spread
  __shared__ __align__(16) bf16 Wr[32][HD + 8];
  __shared__ __align__(16) bf16 Wx[32][ED + 8];
  __shared__ float gl[64][33];

  const int tid  = threadIdx.x;
  const int lane = tid & 63;
  const int wid  = tid >> 6;
  const int wm   = wid & 3;        // m-fragment (batch rows 16*wm..)
  const int wn   = wid >> 2;       // n-fragment (cols 16*wn..), 0..1
  const int u0   = blockIdx.x * 8;
  const int r16  = lane & 15;
  const int kc   = (lane >> 4) * 8;
  const int arow = 16 * wm + r16;  // batch row for A-frags
  const int brow = 16 * wn + r16;  // LDS row for B-frags

  // epilogue mapping: 256 threads, one (batch, unit-pair) per thread
  const int eb   = (tid & 255) >> 2;   // 0..63
  const int j2   = (tid & 3) * 2;      // unit pair base within the 8 owned units
  const int elen = len[eb];
  const int hidx32 = eb * (HD / 2) + (u0 >> 1) + (tid & 3);

  u32 hp = 0;  // this thread's packed h pair; carries z across the phase switch

  for (int phase = 0; phase < 2; ++phase) {
    const bf16* Wih  = phase ? WihD : WihE;
    const bf16* Whh  = phase ? WhhD : WhhE;
    const float* bsum = phase ? bsumD : bsumE;
    const bf16* Xall = phase ? decX : encX;

    // load this block's weight slices into LDS (rows: gate q = n>>3, unit u0+(n&7))
    for (int idx = tid; idx < 32 * HD; idx += 512) {
      int n = idx >> 9, k = idx & (HD - 1);
      Wr[n][k] = Whh[((n >> 3) * HD + u0 + (n & 7)) * HD + k];
    }
    for (int idx = tid; idx < 32 * ED; idx += 512) {
      int n = idx >> 8, k = idx & (ED - 1);
      Wx[n][k] = Wih[((n >> 3) * HD + u0 + (n & 7)) * ED + k];
    }
    const float bi0 = bsum[0 * HD + u0 + j2], bi1 = bsum[0 * HD + u0 + j2 + 1];
    const float bf0 = bsum[1 * HD + u0 + j2], bf1 = bsum[1 * HD + u0 + j2 + 1];
    const float bg0 = bsum[2 * HD + u0 + j2], bg1 = bsum[2 * HD + u0 + j2 + 1];
    const float bo0 = bsum[3 * HD + u0 + j2], bo1 = bsum[3 * HD + u0 + j2 + 1];
    float c0 = 0.f, c1 = 0.f;
    __syncthreads();

    for (int t = 0; t < ST; ++t) {
      const int step = phase * ST + t;
      const u32* hin32 = hbuf32 + (step & 1) * (NBAT * HD / 2);
      u32* hout32      = hbuf32 + ((step & 1) ^ 1) * (NBAT * HD / 2);
      const bf16* xin = Xall + t * (NBAT * ED);

      // ---- x-part first: L2-hot, overlaps the producers' fire window ----
      f32x4 acc1 = {0.f, 0.f, 0.f, 0.f};
      #pragma unroll
      for (int kk = 0; kk < ED / 32; ++kk) {
        bf16x8 av = *(const bf16x8*)(xin + arow * ED + kk * 32 + kc);
        bf16x8 bv = *(const bf16x8*)(&Wx[brow][kk * 32 + kc]);
        acc1 = __builtin_amdgcn_mfma_f32_16x16x32_bf16(av, bv, acc1, 0, 0, 0);
      }

      // ---- wait for all blocks to have produced h(step) ----
      if (step > 0) {
        if (wid == 0) {
          u32 v = __hip_atomic_load(&flags[lane * 4], __ATOMIC_RELAXED,
                                    __HIP_MEMORY_SCOPE_AGENT);
          while (!__all((int)(v >= (u32)step))) {
            __builtin_amdgcn_s_sleep(1);
            v = __hip_atomic_load(&flags[lane * 4], __ATOMIC_RELAXED,
                                  __HIP_MEMORY_SCOPE_AGENT);
          }
        }
        __syncthreads();
      }

      // ---- h-load: 16 clustered coherent 16B loads, one vmcnt drain ----
      // lane's slice of h row `arow`: bytes arow*1024 + kc*2 + kk*64, kk=0..15
      const u32* hrow = hin32 + arow * (HD / 2) + (kc >> 1);
      f32x4 h00, h01, h02, h03, h04, h05, h06, h07;
      f32x4 h08, h09, h10, h11, h12, h13, h14, h15;
      asm volatile(
          "global_load_dwordx4 %0,  %16, off sc0 sc1\n\t"
          "global_load_dwordx4 %1,  %16, off offset:64 sc0 sc1\n\t"
          "global_load_dwordx4 %2,  %16, off offset:128 sc0 sc1\n\t"
          "global_load_dwordx4 %3,  %16, off offset:192 sc0 sc1\n\t"
          "global_load_dwordx4 %4,  %16, off offset:256 sc0 sc1\n\t"
          "global_load_dwordx4 %5,  %16, off offset:320 sc0 sc1\n\t"
          "global_load_dwordx4 %6,  %16, off offset:384 sc0 sc1\n\t"
          "global_load_dwordx4 %7,  %16, off offset:448 sc0 sc1\n\t"
          "global_load_dwordx4 %8,  %16, off offset:512 sc0 sc1\n\t"
          "global_load_dwordx4 %9,  %16, off offset:576 sc0 sc1\n\t"
          "global_load_dwordx4 %10, %16, off offset:640 sc0 sc1\n\t"
          "global_load_dwordx4 %11, %16, off offset:704 sc0 sc1\n\t"
          "global_load_dwordx4 %12, %16, off offset:768 sc0 sc1\n\t"
          "global_load_dwordx4 %13, %16, off offset:832 sc0 sc1\n\t"
          "global_load_dwordx4 %14, %16, off offset:896 sc0 sc1\n\t"
          "global_load_dwordx4 %15, %16, off offset:960 sc0 sc1\n\t"
          "s_waitcnt vmcnt(0)"
          : "=&v"(h00), "=&v"(h01), "=&v"(h02), "=&v"(h03),
            "=&v"(h04), "=&v"(h05), "=&v"(h06), "=&v"(h07),
            "=&v"(h08), "=&v"(h09), "=&v"(h10), "=&v"(h11),
            "=&v"(h12), "=&v"(h13), "=&v"(h14), "=&v"(h15)
          : "v"(hrow)
          : "memory");
      __builtin_amdgcn_sched_barrier(0);

      // ---- h-MFMA: two independent accumulation chains for latency ----
      f32x4 accA = {0.f, 0.f, 0.f, 0.f};
      f32x4 accB = {0.f, 0.f, 0.f, 0.f};
      {
        const bf16* wrb = &Wr[brow][kc];
        accA = __builtin_amdgcn_mfma_f32_16x16x32_bf16(asbf8(h00), *(const bf16x8*)(wrb +  0 * 32), accA, 0, 0, 0);
        accB = __builtin_amdgcn_mfma_f32_16x16x32_bf16(asbf8(h01), *(const bf16x8*)(wrb +  1 * 32), accB, 0, 0, 0);
        accA = __builtin_amdgcn_mfma_f32_16x16x32_bf16(asbf8(h02), *(const bf16x8*)(wrb +  2 * 32), accA, 0, 0, 0);
        accB = __builtin_amdgcn_mfma_f32_16x16x32_bf16(asbf8(h03), *(const bf16x8*)(wrb +  3 * 32), accB, 0, 0, 0);
        accA = __builtin_amdgcn_mfma_f32_16x16x32_bf16(asbf8(h04), *(const bf16x8*)(wrb +  4 * 32), accA, 0, 0, 0);
        accB = __builtin_amdgcn_mfma_f32_16x16x32_bf16(asbf8(h05), *(const bf16x8*)(wrb +  5 * 32), accB, 0, 0, 0);
        accA = __builtin_amdgcn_mfma_f32_16x16x32_bf16(asbf8(h06), *(const bf16x8*)(wrb +  6 * 32), accA, 0, 0, 0);
        accB = __builtin_amdgcn_mfma_f32_16x16x32_bf16(asbf8(h07), *(const bf16x8*)(wrb +  7 * 32), accB, 0, 0, 0);
        accA = __builtin_amdgcn_mfma_f32_16x16x32_bf16(asbf8(h08), *(const bf16x8*)(wrb +  8 * 32), accA, 0, 0, 0);
        accB = __builtin_amdgcn_mfma_f32_16x16x32_bf16(asbf8(h09), *(const bf16x8*)(wrb +  9 * 32), accB, 0, 0, 0);
        accA = __builtin_amdgcn_mfma_f32_16x16x32_bf16(asbf8(h10), *(const bf16x8*)(wrb + 10 * 32), accA, 0, 0, 0);
        accB = __builtin_amdgcn_mfma_f32_16x16x32_bf16(asbf8(h11), *(const bf16x8*)(wrb + 11 * 32), accB, 0, 0, 0);
        accA = __builtin_amdgcn_mfma_f32_16x16x32_bf16(asbf8(h12), *(const bf16x8*)(wrb + 12 * 32), accA, 0, 0, 0);
        accB = __builtin_amdgcn_mfma_f32_16x16x32_bf16(asbf8(h13), *(const bf16x8*)(wrb + 13 * 32), accB, 0, 0, 0);
        accA = __builtin_amdgcn_mfma_f32_16x16x32_bf16(asbf8(h14), *(const bf16x8*)(wrb + 14 * 32), accA, 0, 0, 0);
        accB = __builtin_amdgcn_mfma_f32_16x16x32_bf16(asbf8(h15), *(const bf16x8*)(wrb + 15 * 32), accB, 0, 0, 0);
      }
      #pragma unroll
      for (int r = 0; r < 4; ++r)
        gl[16 * wm + (lane >> 4) * 4 + r][16 * wn + r16] = accA[r] + accB[r] + acc1[r];
      __syncthreads();

      // elementwise LSTM cell: 256 threads, two adjacent units each
      if (tid < 256) {
        float gi0 = gl[eb][j2]      + bi0, gi1 = gl[eb][j2 + 1]  + bi1;
        float gf0 = gl[eb][8 + j2]  + bf0, gf1 = gl[eb][9 + j2]  + bf1;
        float gg0 = gl[eb][16 + j2] + bg0, gg1 = gl[eb][17 + j2] + bg1;
        float go0 = gl[eb][24 + j2] + bo0, go1 = gl[eb][25 + j2] + bo1;
        bool upd = (phase == 1) || (t < elen);
        float cn0 = sigm(gf0) * c0 + sigm(gi0) * tanhf(gg0);
        float cn1 = sigm(gf1) * c1 + sigm(gi1) * tanhf(gg1);
        float hn0 = sigm(go0) * tanhf(cn0);
        float hn1 = sigm(go1) * tanhf(cn1);
        if (upd) {
          c0 = cn0; c1 = cn1;
          union { u32 u; bf16 h[2]; } pk;
          pk.h[0] = (bf16)hn0; pk.h[1] = (bf16)hn1;
          hp = pk.u;
        }
        __hip_atomic_store(&hout32[hidx32], hp, __ATOMIC_RELAXED,
                           __HIP_MEMORY_SCOPE_AGENT);
        if (phase == 1) hs32[t * (NBAT * HD / 2) + hidx32] = hp;
      }

      // ---- fire: publish h(step+1) (relaxed; barrier already drained stores) ----
      if (step < 2 * ST - 1) {
        __syncthreads();  // each wave: s_waitcnt vmcnt(0) before s_barrier
        if (tid == 0)
          __hip_atomic_store(&flags[blockIdx.x * 4], (u32)(step + 1),
                             __ATOMIC_RELAXED, __HIP_MEMORY_SCOPE_AGENT);
      }
    }
  }
}

// ---------------- output projection GEMM ----------------
// logits[b][t][v] = sum_h hs[t][b][h] * lin_W[v][h] + lin_b[v]
// M = ST*NBAT = 4096 (row m = t*64+b), N = VO = 32000, K = HD = 512.
// 128x128 tile, BK=64, 4 waves each owning a 64x64 quadrant (4x4 frags).
__global__ __launch_bounds__(256, 2) void k_logits(
    const bf16* __restrict__ hsb, const bf16* __restrict__ Wb,
    const float* __restrict__ linb, float* __restrict__ out)
{
  __shared__ __align__(16) bf16 As[128][72];  // +8 pad -> conflict-free frag reads
  __shared__ __align__(16) bf16 Bs[128][72];
  const int tid  = threadIdx.x;
  const int lane = tid & 63;
  const int wid  = tid >> 6;
  const int wm   = wid >> 1, wn = wid & 1;
  const int bn   = blockIdx.x * 128;
  const int bm   = blockIdx.y * 128;
  const int r16  = lane & 15, kh = lane >> 4;

  f32x4 acc[4][4];
  #pragma unroll
  for (int i = 0; i < 4; ++i)
    #pragma unroll
    for (int j = 0; j < 4; ++j) acc[i][j] = (f32x4){0.f, 0.f, 0.f, 0.f};

  const int srow = tid >> 3;        // 0..31
  const int scol = (tid & 7) * 8;   // 0..56

  for (int kt = 0; kt < HD / 64; ++kt) {
    __syncthreads();
    #pragma unroll
    for (int p = 0; p < 4; ++p) {
      int row = p * 32 + srow;
      *(bf16x8*)(&As[row][scol]) =
          *(const bf16x8*)(hsb + (size_t)(bm + row) * HD + kt * 64 + scol);
      *(bf16x8*)(&Bs[row][scol]) =
          *(const bf16x8*)(Wb + (size_t)(bn + row) * HD + kt * 64 + scol);
    }
    __syncthreads();
    #pragma unroll
    for (int kk = 0; kk < 2; ++kk) {
      bf16x8 af[4], bfv[4];
      #pragma unroll
      for (int i = 0; i < 4; ++i)
        af[i] = *(const bf16x8*)(&As[64 * wm + 16 * i + r16][kk * 32 + kh * 8]);
      #pragma unroll
      for (int j = 0; j < 4; ++j)
        bfv[j] = *(const bf16x8*)(&Bs[64 * wn + 16 * j + r16][kk * 32 + kh * 8]);
      #pragma unroll
      for (int i = 0; i < 4; ++i)
        #pragma unroll
        for (int j = 0; j < 4; ++j)
          acc[i][j] = __builtin_amdgcn_mfma_f32_16x16x32_bf16(af[i], bfv[j], acc[i][j], 0, 0, 0);
    }
  }

  #pragma unroll
  for (int j = 0; j < 4; ++j) {
    int ncol = bn + 64 * wn + 16 * j + r16;
    float bias = linb[ncol];
    #pragma unroll
    for (int i = 0; i < 4; ++i) {
      int mbase = bm + 64 * wm + 16 * i + kh * 4;
      #pragma unroll
      for (int r = 0; r < 4; ++r) {
        int m = mbase + r;
        int b = m & 63, t = m >> 6;
        out[(size_t)(b * ST + t) * VO + ncol] = acc[i][j][r] + bias;
      }
    }
  }
}

// ---------------- host ----------------

extern "C" void kernel_launch(void* const* d_in, const int* in_sizes, int n_in,
                              void* d_out, int out_size, void* d_ws, size_t ws_size,
                              hipStream_t stream) {
  const int*   toks = (const int*)d_in[0];
  const float* emb  = (const float*)d_in[1];
  const float* eWih = (const float*)d_in[2];
  const float* eWhh = (const float*)d_in[3];
  const float* ebih = (const float*)d_in[4];
  const float* ebhh = (const float*)d_in[5];
  const float* dWih = (const float*)d_in[6];
  const float* dWhh = (const float*)d_in[7];
  const float* dbih = (const float*)d_in[8];
  const float* dbhh = (const float*)d_in[9];
  const float* linW = (const float*)d_in[10];
  const float* linb = (const float*)d_in[11];
  float* out = (float*)d_out;

  char* ws = (char*)d_ws;
  size_t off = 0;
  auto alloc = [&](size_t bytes) {
    void* p = ws + off;
    off = (off + bytes + 255) & ~(size_t)255;
    return p;
  };
  bf16* encX  = (bf16*)alloc((size_t)ST * NBAT * ED * 2);
  bf16* decX  = (bf16*)alloc((size_t)ST * NBAT * ED * 2);
  bf16* WihEb = (bf16*)alloc((size_t)G4 * ED * 2);
  bf16* WhhEb = (bf16*)alloc((size_t)G4 * HD * 2);
  bf16* WihDb = (bf16*)alloc((size_t)G4 * ED * 2);
  bf16* WhhDb = (bf16*)alloc((size_t)G4 * HD * 2);
  bf16* WbL   = (bf16*)alloc((size_t)VO * HD * 2);
  float* bsumE = (float*)alloc(G4 * 4);
  float* bsumD = (float*)alloc(G4 * 4);
  u32*  hbuf  = (u32*)alloc((size_t)2 * NBAT * HD * 2);
  u32*  hs    = (u32*)alloc((size_t)ST * NBAT * HD * 2);
  int*  len   = (int*)alloc(NBAT * 4);
  u32*  flags = (u32*)alloc(1024);

  hipMemsetAsync(hbuf, 0, (size_t)2 * NBAT * HD * 2, stream);
  hipMemsetAsync(flags, 0, 1024, stream);

  k_lengths<<<1, 64, 0, stream>>>(toks, len);
  k_bias<<<(G4 + 255) / 256, 256, 0, stream>>>(ebih, ebhh, bsumE);
  k_bias<<<(G4 + 255) / 256, 256, 0, stream>>>(dbih, dbhh, bsumD);
  k_cast<<<(G4 * ED + 255) / 256, 256, 0, stream>>>(eWih, WihEb, G4 * ED);
  k_cast<<<(G4 * HD + 255) / 256, 256, 0, stream>>>(eWhh, WhhEb, G4 * HD);
  k_cast<<<(G4 * ED + 255) / 256, 256, 0, stream>>>(dWih, WihDb, G4 * ED);
  k_cast<<<(G4 * HD + 255) / 256, 256, 0, stream>>>(dWhh, WhhDb, G4 * HD);
  k_cast<<<(VO * HD + 255) / 256, 256, 0, stream>>>(linW, WbL, VO * HD);
  k_gather<<<(ST * NBAT * ED + 255) / 256, 256, 0, stream>>>(toks, emb, encX, decX);

  k_lstm<<<LSTM_BLOCKS, 512, 0, stream>>>(encX, decX, WihEb, WhhEb, WihDb, WhhDb,
                                          bsumE, bsumD, len, hbuf, hs, flags);

  k_logits<<<dim3(VO / 128, (ST * NBAT) / 128), 256, 0, stream>>>((const bf16*)hs, WbL, linb, out);
}

// Round 6
// 1239.445 us; speedup vs baseline: 1.3435x; 1.0216x over previous
//
#include <hip/hip_runtime.h>
#include <math.h>

// Problem constants
#define ST 64      // sequence length T
#define NBAT 64    // batch B
#define ED 256     // embedding dim E
#define HD 512     // hidden dim H
#define G4 2048    // 4*H
#define VO 32000   // vocab
#define LSTM_BLOCKS 64
#define SLOT32 (NBAT * HD / 2)   // u32s per h slot (64 KB)

typedef unsigned int u32;
typedef unsigned long long u64;
typedef __bf16 bf16;
typedef bf16 bf16x8 __attribute__((ext_vector_type(8)));
typedef float f32x4 __attribute__((ext_vector_type(4)));

__device__ __forceinline__ float sigm(float x) { return 1.f / (1.f + expf(-x)); }

// ---------------- prep kernels ----------------

__global__ void k_lengths(const int* __restrict__ toks, int* __restrict__ len) {
  int b = threadIdx.x;
  if (b < NBAT) {
    int n = 0;
    for (int t = 0; t < ST; ++t) n += (toks[b * ST + t] != 0) ? 1 : 0;
    len[b] = n;
  }
}

__global__ void k_cast(const float* __restrict__ src, bf16* __restrict__ dst, int n) {
  int i = blockIdx.x * blockDim.x + threadIdx.x;
  if (i < n) dst[i] = (bf16)src[i];
}

__global__ void k_bias(const float* __restrict__ a, const float* __restrict__ b,
                       float* __restrict__ o) {
  int i = blockIdx.x * blockDim.x + threadIdx.x;
  if (i < G4) o[i] = a[i] + b[i];
}

// encX[t][b][e] = emb[toks[b][t]][e]; decX[t][b][e] = emb[t==0 ? 1 : toks[b][t-1]][e]
__global__ void k_gather(const int* __restrict__ toks, const float* __restrict__ emb,
                         bf16* __restrict__ encX, bf16* __restrict__ decX) {
  int i = blockIdx.x * blockDim.x + threadIdx.x;
  if (i >= ST * NBAT * ED) return;
  int e = i % ED;
  int tb = i / ED;
  int b = tb % NBAT;
  int t = tb / NBAT;
  int te = toks[b * ST + t];
  encX[i] = (bf16)emb[te * ED + e];
  int td = (t == 0) ? 1 : toks[b * ST + t - 1];
  decX[i] = (bf16)emb[td * ED + e];
}

// ---------------- persistent LSTM kernel ----------------
//
// Per-step h slots (no buffer reuse) + cached consumer loads:
//   slot s (64 KB) holds h(s), the input of step s. Producers at step s
//   write slot s+1 via relaxed agent-scope bypass stores; a consumer
//   touches slot s exactly ONCE per launch, so its lines are cold in
//   L1/L2 by construction -> a plain cached load demand-fills from the
//   coherence point and cannot be stale. No buffer_inv/wbl2 anywhere.
//   Kernel-dispatch-boundary acquire invalidates L2 between graph
//   replays, so slots are also fresh across replays.
//   fire(v):  __syncthreads() (each wave s_waitcnt vmcnt(0) -> bypass
//             h-stores acked at coherence point), tid0 relaxed-stores
//             flags[myblock]=v.
//   wait(v):  wave 0: 64 lanes relaxed-load the 64 flags until __all(>=v).
//   No WAR hazard (slots never reused) -> fire needs only store-ack.
//   Decoder slots 65..128 ARE the hs tensor ([t][b][h] contiguous) and
//   feed k_logits directly.
//
// Grid: 64 blocks x 512 threads. Block bk owns hidden units u0..u0+7
// (u0=8*bk) for all 4 gates -> 32 gate columns. Gates tile per step:
// [64 batch x 32 cols], K = 512 (h) + 256 (x). 8 waves: wave w -> m-frag
// (w&3), n-frag (w>>2). Gate col order: [i*8 | f*8 | g*8 | o*8].
__global__ __launch_bounds__(512, 2) void k_lstm(
    const bf16* __restrict__ encX, const bf16* __restrict__ decX,
    const bf16* __restrict__ WihE, const bf16* __restrict__ WhhE,
    const bf16* __restrict__ WihD, const bf16* __restrict__ WhhD,
    const float* __restrict__ bsumE, const float* __restrict__ bsumD,
    const int* __restrict__ len,
    u32* __restrict__ hbuf32,  // [2*ST+1][NBAT][HD/2] per-step h slots
    u32* flags)                // [64] per-block progress, 64B-spaced
{
  // +8 pad per row: stride 1040B/528B -> b128 frag reads spread over banks
  __shared__ __align__(16) bf16 Wr[32][HD + 8];
  __shared__ __align__(16) bf16 Wx[32][ED + 8];
  __shared__ float gl[64][33];

  const int tid  = threadIdx.x;
  const int lane = tid & 63;
  const int wid  = tid >> 6;
  const int wm   = wid & 3;        // m-fragment (batch rows 16*wm..)
  const int wn   = wid >> 2;       // n-fragment (cols 16*wn..), 0..1
  const int u0   = blockIdx.x * 8;
  const int r16  = lane & 15;
  const int kc   = (lane >> 4) * 8;
  const int arow = 16 * wm + r16;  // batch row for A-frags
  const int brow = 16 * wn + r16;  // LDS row for B-frags

  // epilogue mapping: 256 threads, one (batch, unit-pair) per thread
  const int eb   = (tid & 255) >> 2;   // 0..63
  const int j2   = (tid & 3) * 2;      // unit pair base within the 8 owned units
  const int elen = len[eb];
  const int hidx32 = eb * (HD / 2) + (u0 >> 1) + (tid & 3);

  u32 hp = 0;  // this thread's packed h pair; carries z across the phase switch

  for (int phase = 0; phase < 2; ++phase) {
    const bf16* Wih  = phase ? WihD : WihE;
    const bf16* Whh  = phase ? WhhD : WhhE;
    const float* bsum = phase ? bsumD : bsumE;
    const bf16* Xall = phase ? decX : encX;

    // load this block's weight slices into LDS (rows: gate q = n>>3, unit u0+(n&7))
    for (int idx = tid; idx < 32 * HD; idx += 512) {
      int n = idx >> 9, k = idx & (HD - 1);
      Wr[n][k] = Whh[((n >> 3) * HD + u0 + (n & 7)) * HD + k];
    }
    for (int idx = tid; idx < 32 * ED; idx += 512) {
      int n = idx >> 8, k = idx & (ED - 1);
      Wx[n][k] = Wih[((n >> 3) * HD + u0 + (n & 7)) * ED + k];
    }
    const float bi0 = bsum[0 * HD + u0 + j2], bi1 = bsum[0 * HD + u0 + j2 + 1];
    const float bf0 = bsum[1 * HD + u0 + j2], bf1 = bsum[1 * HD + u0 + j2 + 1];
    const float bg0 = bsum[2 * HD + u0 + j2], bg1 = bsum[2 * HD + u0 + j2 + 1];
    const float bo0 = bsum[3 * HD + u0 + j2], bo1 = bsum[3 * HD + u0 + j2 + 1];
    float c0 = 0.f, c1 = 0.f;
    __syncthreads();

    for (int t = 0; t < ST; ++t) {
      const int step = phase * ST + t;
      const u32* hslot = hbuf32 + (size_t)step * SLOT32;        // h(step), read-once
      u32* hout        = hbuf32 + (size_t)(step + 1) * SLOT32;  // h(step+1)
      const bf16* xin  = Xall + t * (NBAT * ED);

      // ---- x-part first: L2-hot, overlaps peers' flag propagation ----
      f32x4 acc1 = {0.f, 0.f, 0.f, 0.f};
      #pragma unroll
      for (int kk = 0; kk < ED / 32; ++kk) {
        bf16x8 av = *(const bf16x8*)(xin + arow * ED + kk * 32 + kc);
        bf16x8 bv = *(const bf16x8*)(&Wx[brow][kk * 32 + kc]);
        acc1 = __builtin_amdgcn_mfma_f32_16x16x32_bf16(av, bv, acc1, 0, 0, 0);
      }

      // ---- wait for all blocks to have produced h(step) ----
      if (step > 0) {
        if (wid == 0) {
          u32 v = __hip_atomic_load(&flags[lane * 16], __ATOMIC_RELAXED,
                                    __HIP_MEMORY_SCOPE_AGENT);
          while (!__all((int)(v >= (u32)step))) {
            __builtin_amdgcn_s_sleep(1);
            v = __hip_atomic_load(&flags[lane * 16], __ATOMIC_RELAXED,
                                  __HIP_MEMORY_SCOPE_AGENT);
          }
        }
        __syncthreads();
      }

      // ---- h-part: plain cached loads (slot is cold-by-construction) ----
      const bf16* hrow = (const bf16*)hslot + arow * HD + kc;
      f32x4 accA = {0.f, 0.f, 0.f, 0.f};
      f32x4 accB = {0.f, 0.f, 0.f, 0.f};
      #pragma unroll
      for (int kk = 0; kk < HD / 32; kk += 2) {
        bf16x8 a0 = *(const bf16x8*)(hrow + kk * 32);
        bf16x8 a1 = *(const bf16x8*)(hrow + (kk + 1) * 32);
        bf16x8 b0 = *(const bf16x8*)(&Wr[brow][kk * 32 + kc]);
        bf16x8 b1 = *(const bf16x8*)(&Wr[brow][(kk + 1) * 32 + kc]);
        accA = __builtin_amdgcn_mfma_f32_16x16x32_bf16(a0, b0, accA, 0, 0, 0);
        accB = __builtin_amdgcn_mfma_f32_16x16x32_bf16(a1, b1, accB, 0, 0, 0);
      }
      #pragma unroll
      for (int r = 0; r < 4; ++r)
        gl[16 * wm + (lane >> 4) * 4 + r][16 * wn + r16] = accA[r] + accB[r] + acc1[r];
      __syncthreads();

      // elementwise LSTM cell: 256 threads, two adjacent units each
      if (tid < 256) {
        float gi0 = gl[eb][j2]      + bi0, gi1 = gl[eb][j2 + 1]  + bi1;
        float gf0 = gl[eb][8 + j2]  + bf0, gf1 = gl[eb][9 + j2]  + bf1;
        float gg0 = gl[eb][16 + j2] + bg0, gg1 = gl[eb][17 + j2] + bg1;
        float go0 = gl[eb][24 + j2] + bo0, go1 = gl[eb][25 + j2] + bo1;
        bool upd = (phase == 1) || (t < elen);
        float cn0 = sigm(gf0) * c0 + sigm(gi0) * tanhf(gg0);
        float cn1 = sigm(gf1) * c1 + sigm(gi1) * tanhf(gg1);
        float hn0 = sigm(go0) * tanhf(cn0);
        float hn1 = sigm(go1) * tanhf(cn1);
        if (upd) {
          c0 = cn0; c1 = cn1;
          union { u32 u; bf16 h[2]; } pk;
          pk.h[0] = (bf16)hn0; pk.h[1] = (bf16)hn1;
          hp = pk.u;
        }
        // bypass store -> coherence point; consumers demand-fill fresh
        __hip_atomic_store(&hout[hidx32], hp, __ATOMIC_RELAXED,
                           __HIP_MEMORY_SCOPE_AGENT);
      }

      // ---- fire: publish h(step+1) (stores drained by the barrier) ----
      if (step < 2 * ST - 1) {
        __syncthreads();  // each wave: s_waitcnt vmcnt(0) before s_barrier
        if (tid == 0)
          __hip_atomic_store(&flags[blockIdx.x * 16], (u32)(step + 1),
                             __ATOMIC_RELAXED, __HIP_MEMORY_SCOPE_AGENT);
      }
    }
  }
}

// ---------------- output projection GEMM ----------------
// logits[b][t][v] = sum_h hs[t][b][h] * lin_W[v][h] + lin_b[v]
// hs = h-slots 65..128 (contiguous [t][b][h]).
// M = ST*NBAT = 4096 (row m = t*64+b), N = VO = 32000, K = HD = 512.
// 128x128 tile, BK=64, 4 waves each owning a 64x64 quadrant (4x4 frags).
__global__ __launch_bounds__(256, 2) void k_logits(
    const bf16* __restrict__ hsb, const bf16* __restrict__ Wb,
    const float* __restrict__ linb, float* __restrict__ out)
{
  __shared__ __align__(16) bf16 As[128][72];  // +8 pad -> conflict-free frag reads
  __shared__ __align__(16) bf16 Bs[128][72];
  const int tid  = threadIdx.x;
  const int lane = tid & 63;
  const int wid  = tid >> 6;
  const int wm   = wid >> 1, wn = wid & 1;
  const int bn   = blockIdx.x * 128;
  const int bm   = blockIdx.y * 128;
  const int r16  = lane & 15, kh = lane >> 4;

  f32x4 acc[4][4];
  #pragma unroll
  for (int i = 0; i < 4; ++i)
    #pragma unroll
    for (int j = 0; j < 4; ++j) acc[i][j] = (f32x4){0.f, 0.f, 0.f, 0.f};

  const int srow = tid >> 3;        // 0..31
  const int scol = (tid & 7) * 8;   // 0..56

  for (int kt = 0; kt < HD / 64; ++kt) {
    __syncthreads();
    #pragma unroll
    for (int p = 0; p < 4; ++p) {
      int row = p * 32 + srow;
      *(bf16x8*)(&As[row][scol]) =
          *(const bf16x8*)(hsb + (size_t)(bm + row) * HD + kt * 64 + scol);
      *(bf16x8*)(&Bs[row][scol]) =
          *(const bf16x8*)(Wb + (size_t)(bn + row) * HD + kt * 64 + scol);
    }
    __syncthreads();
    #pragma unroll
    for (int kk = 0; kk < 2; ++kk) {
      bf16x8 af[4], bfv[4];
      #pragma unroll
      for (int i = 0; i < 4; ++i)
        af[i] = *(const bf16x8*)(&As[64 * wm + 16 * i + r16][kk * 32 + kh * 8]);
      #pragma unroll
      for (int j = 0; j < 4; ++j)
        bfv[j] = *(const bf16x8*)(&Bs[64 * wn + 16 * j + r16][kk * 32 + kh * 8]);
      #pragma unroll
      for (int i = 0; i < 4; ++i)
        #pragma unroll
        for (int j = 0; j < 4; ++j)
          acc[i][j] = __builtin_amdgcn_mfma_f32_16x16x32_bf16(af[i], bfv[j], acc[i][j], 0, 0, 0);
    }
  }

  #pragma unroll
  for (int j = 0; j < 4; ++j) {
    int ncol = bn + 64 * wn + 16 * j + r16;
    float bias = linb[ncol];
    #pragma unroll
    for (int i = 0; i < 4; ++i) {
      int mbase = bm + 64 * wm + 16 * i + kh * 4;
      #pragma unroll
      for (int r = 0; r < 4; ++r) {
        int m = mbase + r;
        int b = m & 63, t = m >> 6;
        out[(size_t)(b * ST + t) * VO + ncol] = acc[i][j][r] + bias;
      }
    }
  }
}

// ---------------- host ----------------

extern "C" void kernel_launch(void* const* d_in, const int* in_sizes, int n_in,
                              void* d_out, int out_size, void* d_ws, size_t ws_size,
                              hipStream_t stream) {
  const int*   toks = (const int*)d_in[0];
  const float* emb  = (const float*)d_in[1];
  const float* eWih = (const float*)d_in[2];
  const float* eWhh = (const float*)d_in[3];
  const float* ebih = (const float*)d_in[4];
  const float* ebhh = (const float*)d_in[5];
  const float* dWih = (const float*)d_in[6];
  const float* dWhh = (const float*)d_in[7];
  const float* dbih = (const float*)d_in[8];
  const float* dbhh = (const float*)d_in[9];
  const float* linW = (const float*)d_in[10];
  const float* linb = (const float*)d_in[11];
  float* out = (float*)d_out;

  char* ws = (char*)d_ws;
  size_t off = 0;
  auto alloc = [&](size_t bytes) {
    void* p = ws + off;
    off = (off + bytes + 255) & ~(size_t)255;
    return p;
  };
  bf16* encX  = (bf16*)alloc((size_t)ST * NBAT * ED * 2);
  bf16* decX  = (bf16*)alloc((size_t)ST * NBAT * ED * 2);
  bf16* WihEb = (bf16*)alloc((size_t)G4 * ED * 2);
  bf16* WhhEb = (bf16*)alloc((size_t)G4 * HD * 2);
  bf16* WihDb = (bf16*)alloc((size_t)G4 * ED * 2);
  bf16* WhhDb = (bf16*)alloc((size_t)G4 * HD * 2);
  bf16* WbL   = (bf16*)alloc((size_t)VO * HD * 2);
  float* bsumE = (float*)alloc(G4 * 4);
  float* bsumD = (float*)alloc(G4 * 4);
  u32*  hbuf  = (u32*)alloc((size_t)(2 * ST + 1) * SLOT32 * 4);  // 129 x 64 KB
  int*  len   = (int*)alloc(NBAT * 4);
  u32*  flags = (u32*)alloc(4096);

  // slot 0 (h(0) = 0) and flags must be clean every launch
  hipMemsetAsync(hbuf, 0, (size_t)SLOT32 * 4, stream);
  hipMemsetAsync(flags, 0, 4096, stream);

  k_lengths<<<1, 64, 0, stream>>>(toks, len);
  k_bias<<<(G4 + 255) / 256, 256, 0, stream>>>(ebih, ebhh, bsumE);
  k_bias<<<(G4 + 255) / 256, 256, 0, stream>>>(dbih, dbhh, bsumD);
  k_cast<<<(G4 * ED + 255) / 256, 256, 0, stream>>>(eWih, WihEb, G4 * ED);
  k_cast<<<(G4 * HD + 255) / 256, 256, 0, stream>>>(eWhh, WhhEb, G4 * HD);
  k_cast<<<(G4 * ED + 255) / 256, 256, 0, stream>>>(dWih, WihDb, G4 * ED);
  k_cast<<<(G4 * HD + 255) / 256, 256, 0, stream>>>(dWhh, WhhDb, G4 * HD);
  k_cast<<<(VO * HD + 255) / 256, 256, 0, stream>>>(linW, WbL, VO * HD);
  k_gather<<<(ST * NBAT * ED + 255) / 256, 256, 0, stream>>>(toks, emb, encX, decX);

  k_lstm<<<LSTM_BLOCKS, 512, 0, stream>>>(encX, decX, WihEb, WhhEb, WihDb, WhhDb,
                                          bsumE, bsumD, len, hbuf, flags);

  // decoder outputs = slots 65..128, contiguous [t][b][h]
  const bf16* hsb = (const bf16*)(hbuf + (size_t)(ST + 1) * SLOT32);
  k_logits<<<dim3(VO / 128, (ST * NBAT) / 128), 256, 0, stream>>>(hsb, WbL, linb, out);
}

// Round 7
// 1208.642 us; speedup vs baseline: 1.3777x; 1.0255x over previous
//
#include <hip/hip_runtime.h>
#include <math.h>

// Problem constants
#define ST 64      // sequence length T
#define NBAT 64    // batch B
#define ED 256     // embedding dim E
#define HD 512     // hidden dim H
#define G4 2048    // 4*H
#define VO 32000   // vocab
#define NWORK 64               // worker blocks
#define SLOT32 (NBAT * HD / 2) // u32s per h slot (64 KB)
#define PROBE_STEPS 32

typedef unsigned int u32;
typedef __bf16 bf16;
typedef bf16 bf16x8 __attribute__((ext_vector_type(8)));
typedef float f32x4 __attribute__((ext_vector_type(4)));

__device__ __forceinline__ float sigm(float x) { return 1.f / (1.f + expf(-x)); }

// ---------------- prep kernels ----------------

__global__ void k_lengths(const int* __restrict__ toks, int* __restrict__ len) {
  int b = threadIdx.x;
  if (b < NBAT) {
    int n = 0;
    for (int t = 0; t < ST; ++t) n += (toks[b * ST + t] != 0) ? 1 : 0;
    len[b] = n;
  }
}

__global__ void k_cast(const float* __restrict__ src, bf16* __restrict__ dst, int n) {
  int i = blockIdx.x * blockDim.x + threadIdx.x;
  if (i < n) dst[i] = (bf16)src[i];
}

__global__ void k_bias(const float* __restrict__ a, const float* __restrict__ b,
                       float* __restrict__ o) {
  int i = blockIdx.x * blockDim.x + threadIdx.x;
  if (i < G4) o[i] = a[i] + b[i];
}

// encX[t][b][e] = emb[toks[b][t]][e]; decX[t][b][e] = emb[t==0 ? 1 : toks[b][t-1]][e]
__global__ void k_gather(const int* __restrict__ toks, const float* __restrict__ emb,
                         bf16* __restrict__ encX, bf16* __restrict__ decX) {
  int i = blockIdx.x * blockDim.x + threadIdx.x;
  if (i >= ST * NBAT * ED) return;
  int e = i % ED;
  int tb = i / ED;
  int b = tb % NBAT;
  int t = tb / NBAT;
  int te = toks[b * ST + t];
  encX[i] = (bf16)emb[te * ED + e];
  int td = (t == 0) ? 1 : toks[b * ST + t - 1];
  decX[i] = (bf16)emb[td * ED + e];
}

// ---------------- persistent LSTM kernel ----------------
//
// Sync: aggregator barrier with dense flags.
//   workers fire:  __syncthreads (vmcnt(0) -> bypass h-stores acked at the
//                  coherence point), tid0 relaxed-stores flags[blk]=v
//                  (flags = 64 contiguous u32 -> 4 lines total).
//   aggregator:    block 0, wave 0: polls the 4 flag lines until
//                  __all(flags >= v), then relaxed-stores go=v (1 line).
//   workers wait:  wave 0 polls the single go line until go >= step.
//   Rationale: rounds 2-6 polled 64 scattered lines from 64 CUs
//   continuously (~4096 concurrent line reads at the coherence point) --
//   suspected fabric congestion as the unexplained ~4.5 us/step.
//
// h exchange: per-step slots hx[step][block][b][8] (block-major!).
//   Producer block writes ONE contiguous 1 KB run of bypass stores
//   (pure full-line writes, no partial-line RMW at the memory side).
//   Consumer A-fragment (8 contiguous h of one batch row) = exactly one
//   16 B chunk: addr = (kk*4+hi)*1024 + arow*16. Plain cached loads --
//   slot is cold-by-construction per launch (round 6 protocol).
//   Decoder h additionally stored PLAIN to hs[t][b][h] (local L2, cheap);
//   dispatch-boundary release makes it visible to k_logits.
//
// MODE: 0 = real (2 phases x 64 steps, 65 blocks: 1 agg + 64 workers)
//       1 = probe, work only, no sync   (1 phase x 32 steps, 64 blocks)
//       2 = probe, sync only, no work   (1 phase x 32 steps, 65 blocks)
template <int MODE>
__global__ __launch_bounds__(512, 2) void k_lstm(
    const bf16* __restrict__ encX, const bf16* __restrict__ decX,
    const bf16* __restrict__ WihE, const bf16* __restrict__ WhhE,
    const bf16* __restrict__ WihD, const bf16* __restrict__ WhhD,
    const float* __restrict__ bsumE, const float* __restrict__ bsumD,
    const int* __restrict__ len,
    u32* __restrict__ hx32,    // [TOT+1][NWORK][NBAT][8/2] per-step h slots
    u32* __restrict__ hs32,    // [ST][NBAT][HD/2] decoder h (plain stores)
    u32* flags,                // [64] dense worker progress
    u32* go)                   // [1] aggregator broadcast
{
  constexpr int  NPH  = (MODE == 0) ? 2 : 1;
  constexpr int  NST  = (MODE == 0) ? ST : PROBE_STEPS;
  constexpr int  TOT  = NPH * NST;
  constexpr bool SYNC = (MODE != 1);
  constexpr bool COMP = (MODE != 2);

  const int tid  = threadIdx.x;
  const int lane = tid & 63;
  const int wid  = tid >> 6;

  // ---- aggregator block ----
  if (SYNC && blockIdx.x == 0) {
    if (tid < 64) {
      for (int v = 1; v <= TOT - 1; ++v) {
        u32 f = __hip_atomic_load(&flags[lane], __ATOMIC_RELAXED,
                                  __HIP_MEMORY_SCOPE_AGENT);
        while (!__all((int)(f >= (u32)v))) {
          __builtin_amdgcn_s_sleep(1);
          f = __hip_atomic_load(&flags[lane], __ATOMIC_RELAXED,
                                __HIP_MEMORY_SCOPE_AGENT);
        }
        if (lane == 0)
          __hip_atomic_store(go, (u32)v, __ATOMIC_RELAXED,
                             __HIP_MEMORY_SCOPE_AGENT);
      }
    }
    return;
  }
  const int blk = SYNC ? (int)blockIdx.x - 1 : (int)blockIdx.x;

  // +8 pad per row keeps b128 fragment reads spread over banks
  __shared__ __align__(16) bf16 Wr[32][HD + 8];
  __shared__ __align__(16) bf16 Wx[32][ED + 8];
  __shared__ float gl[64][33];

  const int wm   = wid & 3;        // m-fragment (batch rows 16*wm..)
  const int wn   = wid >> 2;       // n-fragment (cols 16*wn..), 0..1
  const int u0   = blk * 8;
  const int r16  = lane & 15;
  const int kc   = (lane >> 4) * 8;
  const int hi   = lane >> 4;      // which 8-chunk of the 32-K slice
  const int arow = 16 * wm + r16;  // batch row for A-frags
  const int brow = 16 * wn + r16;  // LDS row for B-frags

  // epilogue mapping: 256 threads, one (batch, unit-pair) per thread
  const int eb   = (tid & 255) >> 2;   // 0..63
  const int j2   = (tid & 3) * 2;      // unit pair base within 8 owned units
  const int elen = len[eb];

  u32 hp = 0;  // packed h pair; carries z across the phase switch

  for (int phase = 0; phase < NPH; ++phase) {
    const bf16* Wih  = phase ? WihD : WihE;
    const bf16* Whh  = phase ? WhhD : WhhE;
    const float* bsum = phase ? bsumD : bsumE;
    const bf16* Xall = phase ? decX : encX;

    if (COMP) {
      // weight slices -> LDS (rows: gate q = n>>3, unit u0+(n&7))
      for (int idx = tid; idx < 32 * HD; idx += 512) {
        int n = idx >> 9, k = idx & (HD - 1);
        Wr[n][k] = Whh[((n >> 3) * HD + u0 + (n & 7)) * HD + k];
      }
      for (int idx = tid; idx < 32 * ED; idx += 512) {
        int n = idx >> 8, k = idx & (ED - 1);
        Wx[n][k] = Wih[((n >> 3) * HD + u0 + (n & 7)) * ED + k];
      }
      __syncthreads();
    }
    const float bi0 = bsum[0 * HD + u0 + j2], bi1 = bsum[0 * HD + u0 + j2 + 1];
    const float bf0 = bsum[1 * HD + u0 + j2], bf1 = bsum[1 * HD + u0 + j2 + 1];
    const float bg0 = bsum[2 * HD + u0 + j2], bg1 = bsum[2 * HD + u0 + j2 + 1];
    const float bo0 = bsum[3 * HD + u0 + j2], bo1 = bsum[3 * HD + u0 + j2 + 1];
    float c0 = 0.f, c1 = 0.f;

    for (int t = 0; t < NST; ++t) {
      const int step = phase * NST + t;
      u32* hxout = hx32 + (size_t)(step + 1) * SLOT32 + blk * 256;

      f32x4 acc1 = {0.f, 0.f, 0.f, 0.f};
      if (COMP) {
        // ---- x-part first: overlaps peers' fire propagation ----
        const bf16* xin = Xall + t * (NBAT * ED);
        #pragma unroll
        for (int kk = 0; kk < ED / 32; ++kk) {
          bf16x8 av = *(const bf16x8*)(xin + arow * ED + kk * 32 + kc);
          bf16x8 bv = *(const bf16x8*)(&Wx[brow][kk * 32 + kc]);
          acc1 = __builtin_amdgcn_mfma_f32_16x16x32_bf16(av, bv, acc1, 0, 0, 0);
        }
      }

      // ---- wait: poll the single go line ----
      if (SYNC && step > 0) {
        if (wid == 0) {
          u32 v = __hip_atomic_load(go, __ATOMIC_RELAXED,
                                    __HIP_MEMORY_SCOPE_AGENT);
          while (v < (u32)step) {
            __builtin_amdgcn_s_sleep(2);
            v = __hip_atomic_load(go, __ATOMIC_RELAXED,
                                  __HIP_MEMORY_SCOPE_AGENT);
          }
        }
        __syncthreads();
      }

      if (COMP) {
        // ---- h-part: cached cold-miss loads, chunk-mapped layout ----
        const bf16* hbase = (const bf16*)(hx32 + (size_t)step * SLOT32);
        const bf16* hptr  = hbase + (size_t)hi * 512 + arow * 8;
        f32x4 accA = {0.f, 0.f, 0.f, 0.f};
        f32x4 accB = {0.f, 0.f, 0.f, 0.f};
        #pragma unroll
        for (int kk = 0; kk < HD / 32; kk += 2) {
          bf16x8 a0 = *(const bf16x8*)(hptr + (size_t)kk * 2048);
          bf16x8 a1 = *(const bf16x8*)(hptr + (size_t)(kk + 1) * 2048);
          bf16x8 b0 = *(const bf16x8*)(&Wr[brow][kk * 32 + kc]);
          bf16x8 b1 = *(const bf16x8*)(&Wr[brow][(kk + 1) * 32 + kc]);
          accA = __builtin_amdgcn_mfma_f32_16x16x32_bf16(a0, b0, accA, 0, 0, 0);
          accB = __builtin_amdgcn_mfma_f32_16x16x32_bf16(a1, b1, accB, 0, 0, 0);
        }
        #pragma unroll
        for (int r = 0; r < 4; ++r)
          gl[16 * wm + (lane >> 4) * 4 + r][16 * wn + r16] = accA[r] + accB[r] + acc1[r];
        __syncthreads();

        // elementwise LSTM cell: 256 threads, two adjacent units each
        if (tid < 256) {
          float gi0 = gl[eb][j2]      + bi0, gi1 = gl[eb][j2 + 1]  + bi1;
          float gf0 = gl[eb][8 + j2]  + bf0, gf1 = gl[eb][9 + j2]  + bf1;
          float gg0 = gl[eb][16 + j2] + bg0, gg1 = gl[eb][17 + j2] + bg1;
          float go0 = gl[eb][24 + j2] + bo0, go1 = gl[eb][25 + j2] + bo1;
          bool upd = (phase == NPH - 1 && MODE == 0) || (t < elen);
          if (MODE == 0 && NPH == 2 && phase == 1) upd = true;
          float cn0 = sigm(gf0) * c0 + sigm(gi0) * tanhf(gg0);
          float cn1 = sigm(gf1) * c1 + sigm(gi1) * tanhf(gg1);
          float hn0 = sigm(go0) * tanhf(cn0);
          float hn1 = sigm(go1) * tanhf(cn1);
          if (upd) {
            c0 = cn0; c1 = cn1;
            union { u32 u; bf16 h[2]; } pk;
            pk.h[0] = (bf16)hn0; pk.h[1] = (bf16)hn1;
            hp = pk.u;
          }
          // full-line bypass store: contiguous 1 KB per block
          __hip_atomic_store(&hxout[tid], hp, __ATOMIC_RELAXED,
                             __HIP_MEMORY_SCOPE_AGENT);
          // decoder h also plain-stored to [t][b][h] for k_logits
          if (MODE == 0 && phase == 1)
            hs32[t * (NBAT * HD / 2) + eb * (HD / 2) + blk * 4 + (tid & 3)] = hp;
        }
      } else {
        // MODE 2: protocol-only probe -- same store footprint, no compute
        if (tid < 256)
          __hip_atomic_store(&hxout[tid], (u32)step, __ATOMIC_RELAXED,
                             __HIP_MEMORY_SCOPE_AGENT);
      }

      // gl-reuse guard + drain bypass stores (vmcnt(0) per wave), then fire
      __syncthreads();
      if (SYNC && step < TOT - 1 && tid == 0)
        __hip_atomic_store(&flags[blk], (u32)(step + 1), __ATOMIC_RELAXED,
                           __HIP_MEMORY_SCOPE_AGENT);
    }
  }
}

// ---------------- output projection GEMM ----------------
// logits[b][t][v] = sum_h hs[t][b][h] * lin_W[v][h] + lin_b[v]
// M = ST*NBAT = 4096 (row m = t*64+b), N = VO = 32000, K = HD = 512.
// 128x128 tile, BK=64, 4 waves each owning a 64x64 quadrant (4x4 frags).
__global__ __launch_bounds__(256, 2) void k_logits(
    const bf16* __restrict__ hsb, const bf16* __restrict__ Wb,
    const float* __restrict__ linb, float* __restrict__ out)
{
  __shared__ __align__(16) bf16 As[128][72];  // +8 pad -> conflict-free frag reads
  __shared__ __align__(16) bf16 Bs[128][72];
  const int tid  = threadIdx.x;
  const int lane = tid & 63;
  const int wid  = tid >> 6;
  const int wm   = wid >> 1, wn = wid & 1;
  const int bn   = blockIdx.x * 128;
  const int bm   = blockIdx.y * 128;
  const int r16  = lane & 15, kh = lane >> 4;

  f32x4 acc[4][4];
  #pragma unroll
  for (int i = 0; i < 4; ++i)
    #pragma unroll
    for (int j = 0; j < 4; ++j) acc[i][j] = (f32x4){0.f, 0.f, 0.f, 0.f};

  const int srow = tid >> 3;        // 0..31
  const int scol = (tid & 7) * 8;   // 0..56

  for (int kt = 0; kt < HD / 64; ++kt) {
    __syncthreads();
    #pragma unroll
    for (int p = 0; p < 4; ++p) {
      int row = p * 32 + srow;
      *(bf16x8*)(&As[row][scol]) =
          *(const bf16x8*)(hsb + (size_t)(bm + row) * HD + kt * 64 + scol);
      *(bf16x8*)(&Bs[row][scol]) =
          *(const bf16x8*)(Wb + (size_t)(bn + row) * HD + kt * 64 + scol);
    }
    __syncthreads();
    #pragma unroll
    for (int kk = 0; kk < 2; ++kk) {
      bf16x8 af[4], bfv[4];
      #pragma unroll
      for (int i = 0; i < 4; ++i)
        af[i] = *(const bf16x8*)(&As[64 * wm + 16 * i + r16][kk * 32 + kh * 8]);
      #pragma unroll
      for (int j = 0; j < 4; ++j)
        bfv[j] = *(const bf16x8*)(&Bs[64 * wn + 16 * j + r16][kk * 32 + kh * 8]);
      #pragma unroll
      for (int i = 0; i < 4; ++i)
        #pragma unroll
        for (int j = 0; j < 4; ++j)
          acc[i][j] = __builtin_amdgcn_mfma_f32_16x16x32_bf16(af[i], bfv[j], acc[i][j], 0, 0, 0);
    }
  }

  #pragma unroll
  for (int j = 0; j < 4; ++j) {
    int ncol = bn + 64 * wn + 16 * j + r16;
    float bias = linb[ncol];
    #pragma unroll
    for (int i = 0; i < 4; ++i) {
      int mbase = bm + 64 * wm + 16 * i + kh * 4;
      #pragma unroll
      for (int r = 0; r < 4; ++r) {
        int m = mbase + r;
        int b = m & 63, t = m >> 6;
        out[(size_t)(b * ST + t) * VO + ncol] = acc[i][j][r] + bias;
      }
    }
  }
}

// ---------------- host ----------------

extern "C" void kernel_launch(void* const* d_in, const int* in_sizes, int n_in,
                              void* d_out, int out_size, void* d_ws, size_t ws_size,
                              hipStream_t stream) {
  const int*   toks = (const int*)d_in[0];
  const float* emb  = (const float*)d_in[1];
  const float* eWih = (const float*)d_in[2];
  const float* eWhh = (const float*)d_in[3];
  const float* ebih = (const float*)d_in[4];
  const float* ebhh = (const float*)d_in[5];
  const float* dWih = (const float*)d_in[6];
  const float* dWhh = (const float*)d_in[7];
  const float* dbih = (const float*)d_in[8];
  const float* dbhh = (const float*)d_in[9];
  const float* linW = (const float*)d_in[10];
  const float* linb = (const float*)d_in[11];
  float* out = (float*)d_out;

  char* ws = (char*)d_ws;
  size_t off = 0;
  auto alloc = [&](size_t bytes) {
    void* p = ws + off;
    off = (off + bytes + 255) & ~(size_t)255;
    return p;
  };
  bf16* encX  = (bf16*)alloc((size_t)ST * NBAT * ED * 2);
  bf16* decX  = (bf16*)alloc((size_t)ST * NBAT * ED * 2);
  bf16* WihEb = (bf16*)alloc((size_t)G4 * ED * 2);
  bf16* WhhEb = (bf16*)alloc((size_t)G4 * HD * 2);
  bf16* WihDb = (bf16*)alloc((size_t)G4 * ED * 2);
  bf16* WhhDb = (bf16*)alloc((size_t)G4 * HD * 2);
  bf16* WbL   = (bf16*)alloc((size_t)VO * HD * 2);
  float* bsumE = (float*)alloc(G4 * 4);
  float* bsumD = (float*)alloc(G4 * 4);
  u32*  hxR   = (u32*)alloc((size_t)(2 * ST + 1) * SLOT32 * 4);       // real: 129 slots
  u32*  hxP   = (u32*)alloc((size_t)(PROBE_STEPS + 1) * SLOT32 * 4);  // probes: 33 slots
  u32*  hs    = (u32*)alloc((size_t)ST * NBAT * HD * 2);              // [t][b][h]
  int*  len   = (int*)alloc(NBAT * 4);
  u32*  sync  = (u32*)alloc(4096);
  u32* flagsR = sync;            // 64 u32 dense (4 lines)
  u32* goR    = sync + 64;       // own line (byte 256)
  u32* flagsP = sync + 128;      // byte 512
  u32* goP    = sync + 192;      // byte 768

  // slot 0 (h(0)=0) + all sync words must be clean every launch
  hipMemsetAsync(hxR, 0, (size_t)SLOT32 * 4, stream);
  hipMemsetAsync(sync, 0, 4096, stream);

  k_lengths<<<1, 64, 0, stream>>>(toks, len);
  k_bias<<<(G4 + 255) / 256, 256, 0, stream>>>(ebih, ebhh, bsumE);
  k_bias<<<(G4 + 255) / 256, 256, 0, stream>>>(dbih, dbhh, bsumD);
  k_cast<<<(G4 * ED + 255) / 256, 256, 0, stream>>>(eWih, WihEb, G4 * ED);
  k_cast<<<(G4 * HD + 255) / 256, 256, 0, stream>>>(eWhh, WhhEb, G4 * HD);
  k_cast<<<(G4 * ED + 255) / 256, 256, 0, stream>>>(dWih, WihDb, G4 * ED);
  k_cast<<<(G4 * HD + 255) / 256, 256, 0, stream>>>(dWhh, WhhDb, G4 * HD);
  k_cast<<<(VO * HD + 255) / 256, 256, 0, stream>>>(linW, WbL, VO * HD);
  k_gather<<<(ST * NBAT * ED + 255) / 256, 256, 0, stream>>>(toks, emb, encX, decX);

  // probes (disjoint scratch; timing decomposition only)
  k_lstm<1><<<NWORK, 512, 0, stream>>>(encX, decX, WihEb, WhhEb, WihDb, WhhDb,
                                       bsumE, bsumD, len, hxP, hs, flagsP, goP);
  k_lstm<2><<<NWORK + 1, 512, 0, stream>>>(encX, decX, WihEb, WhhEb, WihDb, WhhDb,
                                           bsumE, bsumD, len, hxP, hs, flagsP, goP);
  // real
  k_lstm<0><<<NWORK + 1, 512, 0, stream>>>(encX, decX, WihEb, WhhEb, WihDb, WhhDb,
                                           bsumE, bsumD, len, hxR, hs, flagsR, goR);

  k_logits<<<dim3(VO / 128, (ST * NBAT) / 128), 256, 0, stream>>>(
      (const bf16*)hs, WbL, linb, out);
}

// Round 8
// 1107.393 us; speedup vs baseline: 1.5037x; 1.0914x over previous
//
#include <hip/hip_runtime.h>
#include <math.h>

// Problem constants
#define ST 64      // sequence length T
#define NBAT 64    // batch B
#define ED 256     // embedding dim E
#define HD 512     // hidden dim H
#define G4 2048    // 4*H
#define VO 32000   // vocab
#define NWORK 64               // worker blocks
#define SLOT32 (NBAT * HD / 2) // u32s per h slot (64 KB)

typedef unsigned int u32;
typedef __bf16 bf16;
typedef bf16 bf16x8 __attribute__((ext_vector_type(8)));
typedef float f32x4 __attribute__((ext_vector_type(4)));

__device__ __forceinline__ float sigm(float x) { return 1.f / (1.f + expf(-x)); }

// ---------------- prep kernels ----------------

__global__ void k_lengths(const int* __restrict__ toks, int* __restrict__ len) {
  int b = threadIdx.x;
  if (b < NBAT) {
    int n = 0;
    for (int t = 0; t < ST; ++t) n += (toks[b * ST + t] != 0) ? 1 : 0;
    len[b] = n;
  }
}

__global__ void k_cast(const float* __restrict__ src, bf16* __restrict__ dst, int n) {
  int i = blockIdx.x * blockDim.x + threadIdx.x;
  if (i < n) dst[i] = (bf16)src[i];
}

__global__ void k_bias(const float* __restrict__ a, const float* __restrict__ b,
                       float* __restrict__ o) {
  int i = blockIdx.x * blockDim.x + threadIdx.x;
  if (i < G4) o[i] = a[i] + b[i];
}

// encX[t][b][e] = emb[toks[b][t]][e]; decX[t][b][e] = emb[t==0 ? 1 : toks[b][t-1]][e]
__global__ void k_gather(const int* __restrict__ toks, const float* __restrict__ emb,
                         bf16* __restrict__ encX, bf16* __restrict__ decX) {
  int i = blockIdx.x * blockDim.x + threadIdx.x;
  if (i >= ST * NBAT * ED) return;
  int e = i % ED;
  int tb = i / ED;
  int b = tb % NBAT;
  int t = tb / NBAT;
  int te = toks[b * ST + t];
  encX[i] = (bf16)emb[te * ED + e];
  int td = (t == 0) ? 1 : toks[b * ST + t - 1];
  decX[i] = (bf16)emb[td * ED + e];
}

// ---------------- persistent LSTM kernel ----------------
//
// Sync: direct dense-flag polling, fused into the h-MFMA.
//   fire(v):  __syncthreads (each wave s_waitcnt vmcnt(0) -> bypass h-stores
//             acked at the coherence point), tid0 relaxed-stores flags[blk]=v.
//             flags = 64 contiguous u32 -> 4 cache lines.
//   wait:     EVERY wave polls flag line g (producers 16g..16g+15) just
//             before consuming K-chunks kk in [4g, 4g+4) -- the first 3/4
//             of the h-MFMA overlaps straggler detection, and there is no
//             aggregator middle-hop (round 7's agg added ~1 RT/step).
//             fence(acquire,wavefront)+sched_barrier(0) after each wait so
//             the compiler cannot speculate the h-loads above the poll.
//
// h exchange: per-step slots hx[step][prod][b][8] (block-major).
//   Producer block writes ONE contiguous 1 KB run of relaxed agent-scope
//   bypass stores (full-line writes). Consumer A-fragment = one 16 B chunk
//   at (4kk+hi)*1024 + arow*16, plain cached load: slot is touched exactly
//   once per launch -> cold in L1/L2 by construction -> demand-fill from
//   the coherence point cannot be stale. No buffer_inv/wbl2 anywhere.
//   Decoder h additionally plain-stored to hs[t][b][h]; the dispatch
//   boundary makes it visible to k_logits.
//
// Grid: 64 blocks x 512 threads. Block bk owns hidden units u0..u0+7
// (u0=8*bk) for all 4 gates -> 32 gate columns. Gates tile per step:
// [64 batch x 32 cols], K = 512 (h) + 256 (x). 8 waves: wave w -> m-frag
// (w&3), n-frag (w>>2). Gate col order: [i*8 | f*8 | g*8 | o*8].
__global__ __launch_bounds__(512, 2) void k_lstm(
    const bf16* __restrict__ encX, const bf16* __restrict__ decX,
    const bf16* __restrict__ WihE, const bf16* __restrict__ WhhE,
    const bf16* __restrict__ WihD, const bf16* __restrict__ WhhD,
    const float* __restrict__ bsumE, const float* __restrict__ bsumD,
    const int* __restrict__ len,
    u32* __restrict__ hx32,    // [2*ST+1][NWORK][NBAT][8/2] per-step h slots
    u32* __restrict__ hs32,    // [ST][NBAT][HD/2] decoder h (plain stores)
    u32* flags)                // [64] dense worker progress
{
  // +8 pad per row keeps b128 fragment reads spread over banks
  __shared__ __align__(16) bf16 Wr[32][HD + 8];
  __shared__ __align__(16) bf16 Wx[32][ED + 8];
  __shared__ float gl[64][33];

  const int tid  = threadIdx.x;
  const int lane = tid & 63;
  const int wid  = tid >> 6;
  const int blk  = blockIdx.x;
  const int wm   = wid & 3;        // m-fragment (batch rows 16*wm..)
  const int wn   = wid >> 2;       // n-fragment (cols 16*wn..), 0..1
  const int u0   = blk * 8;
  const int r16  = lane & 15;
  const int kc   = (lane >> 4) * 8;
  const int hi   = lane >> 4;      // which 8-chunk of the 32-K slice
  const int arow = 16 * wm + r16;  // batch row for A-frags
  const int brow = 16 * wn + r16;  // LDS row for B-frags
  const int fidx = lane & 15;      // flag word within a line

  // epilogue mapping: 256 threads, one (batch, unit-pair) per thread
  const int eb   = (tid & 255) >> 2;   // 0..63
  const int j2   = (tid & 3) * 2;      // unit pair base within 8 owned units
  const int elen = len[eb];

  u32 hp = 0;  // packed h pair; carries z across the phase switch

  for (int phase = 0; phase < 2; ++phase) {
    const bf16* Wih  = phase ? WihD : WihE;
    const bf16* Whh  = phase ? WhhD : WhhE;
    const float* bsum = phase ? bsumD : bsumE;
    const bf16* Xall = phase ? decX : encX;

    // weight slices -> LDS (rows: gate q = n>>3, unit u0+(n&7))
    for (int idx = tid; idx < 32 * HD; idx += 512) {
      int n = idx >> 9, k = idx & (HD - 1);
      Wr[n][k] = Whh[((n >> 3) * HD + u0 + (n & 7)) * HD + k];
    }
    for (int idx = tid; idx < 32 * ED; idx += 512) {
      int n = idx >> 8, k = idx & (ED - 1);
      Wx[n][k] = Wih[((n >> 3) * HD + u0 + (n & 7)) * ED + k];
    }
    const float bi0 = bsum[0 * HD + u0 + j2], bi1 = bsum[0 * HD + u0 + j2 + 1];
    const float bf0 = bsum[1 * HD + u0 + j2], bf1 = bsum[1 * HD + u0 + j2 + 1];
    const float bg0 = bsum[2 * HD + u0 + j2], bg1 = bsum[2 * HD + u0 + j2 + 1];
    const float bo0 = bsum[3 * HD + u0 + j2], bo1 = bsum[3 * HD + u0 + j2 + 1];
    float c0 = 0.f, c1 = 0.f;
    __syncthreads();

    for (int t = 0; t < ST; ++t) {
      const int step = phase * ST + t;
      u32* hxout = hx32 + (size_t)(step + 1) * SLOT32 + blk * 256;
      const bf16* xin = Xall + t * (NBAT * ED);

      // ---- x-part first: overlaps peers' fire propagation ----
      f32x4 acc1 = {0.f, 0.f, 0.f, 0.f};
      #pragma unroll
      for (int kk = 0; kk < ED / 32; ++kk) {
        bf16x8 av = *(const bf16x8*)(xin + arow * ED + kk * 32 + kc);
        bf16x8 bv = *(const bf16x8*)(&Wx[brow][kk * 32 + kc]);
        acc1 = __builtin_amdgcn_mfma_f32_16x16x32_bf16(av, bv, acc1, 0, 0, 0);
      }

      // ---- h-part: 4 flag-line groups, each gating 4 K-chunks ----
      const bf16* hbase = (const bf16*)(hx32 + (size_t)step * SLOT32);
      const bf16* hptr  = hbase + (size_t)hi * 512 + arow * 8;
      f32x4 accA = {0.f, 0.f, 0.f, 0.f};
      f32x4 accB = {0.f, 0.f, 0.f, 0.f};
      #pragma unroll
      for (int g = 0; g < 4; ++g) {
        if (step > 0) {
          const u32* fw = &flags[g * 16 + fidx];
          u32 f = __hip_atomic_load(fw, __ATOMIC_RELAXED, __HIP_MEMORY_SCOPE_AGENT);
          while (!__all((int)(f >= (u32)step))) {
            __builtin_amdgcn_s_sleep(1);
            f = __hip_atomic_load(fw, __ATOMIC_RELAXED, __HIP_MEMORY_SCOPE_AGENT);
          }
          __builtin_amdgcn_fence(__ATOMIC_ACQUIRE, "wavefront");
          __builtin_amdgcn_sched_barrier(0);
        }
        #pragma unroll
        for (int kk = 4 * g; kk < 4 * g + 4; kk += 2) {
          bf16x8 a0 = *(const bf16x8*)(hptr + (size_t)kk * 2048);
          bf16x8 a1 = *(const bf16x8*)(hptr + (size_t)(kk + 1) * 2048);
          bf16x8 b0 = *(const bf16x8*)(&Wr[brow][kk * 32 + kc]);
          bf16x8 b1 = *(const bf16x8*)(&Wr[brow][(kk + 1) * 32 + kc]);
          accA = __builtin_amdgcn_mfma_f32_16x16x32_bf16(a0, b0, accA, 0, 0, 0);
          accB = __builtin_amdgcn_mfma_f32_16x16x32_bf16(a1, b1, accB, 0, 0, 0);
        }
      }
      #pragma unroll
      for (int r = 0; r < 4; ++r)
        gl[16 * wm + (lane >> 4) * 4 + r][16 * wn + r16] = accA[r] + accB[r] + acc1[r];
      __syncthreads();

      // elementwise LSTM cell: 256 threads, two adjacent units each
      if (tid < 256) {
        float gi0 = gl[eb][j2]      + bi0, gi1 = gl[eb][j2 + 1]  + bi1;
        float gf0 = gl[eb][8 + j2]  + bf0, gf1 = gl[eb][9 + j2]  + bf1;
        float gg0 = gl[eb][16 + j2] + bg0, gg1 = gl[eb][17 + j2] + bg1;
        float go0 = gl[eb][24 + j2] + bo0, go1 = gl[eb][25 + j2] + bo1;
        bool upd = (phase == 1) || (t < elen);
        float cn0 = sigm(gf0) * c0 + sigm(gi0) * tanhf(gg0);
        float cn1 = sigm(gf1) * c1 + sigm(gi1) * tanhf(gg1);
        float hn0 = sigm(go0) * tanhf(cn0);
        float hn1 = sigm(go1) * tanhf(cn1);
        if (upd) {
          c0 = cn0; c1 = cn1;
          union { u32 u; bf16 h[2]; } pk;
          pk.h[0] = (bf16)hn0; pk.h[1] = (bf16)hn1;
          hp = pk.u;
        }
        // full-line bypass store: contiguous 1 KB per block
        __hip_atomic_store(&hxout[tid], hp, __ATOMIC_RELAXED,
                           __HIP_MEMORY_SCOPE_AGENT);
        // decoder h also plain-stored to [t][b][h] for k_logits
        if (phase == 1)
          hs32[t * (NBAT * HD / 2) + eb * (HD / 2) + blk * 4 + (tid & 3)] = hp;
      }

      // drain bypass stores (vmcnt(0) per wave) + gl-reuse guard, then fire
      __syncthreads();
      if (step < 2 * ST - 1 && tid == 0)
        __hip_atomic_store(&flags[blk], (u32)(step + 1), __ATOMIC_RELAXED,
                           __HIP_MEMORY_SCOPE_AGENT);
    }
  }
}

// ---------------- output projection GEMM ----------------
// logits[b][t][v] = sum_h hs[t][b][h] * lin_W[v][h] + lin_b[v]
// M = ST*NBAT = 4096 (row m = t*64+b), N = VO = 32000, K = HD = 512.
// 128x128 tile, BK=64, 4 waves each owning a 64x64 quadrant (4x4 frags).
// XCD-aware bijective swizzle: 8000 blocks, 8000 % 8 == 0.
__global__ __launch_bounds__(256, 2) void k_logits(
    const bf16* __restrict__ hsb, const bf16* __restrict__ Wb,
    const float* __restrict__ linb, float* __restrict__ out)
{
  __shared__ __align__(16) bf16 As[128][72];  // +8 pad -> conflict-free frag reads
  __shared__ __align__(16) bf16 Bs[128][72];
  const int tid  = threadIdx.x;
  const int lane = tid & 63;
  const int wid  = tid >> 6;
  const int wm   = wid >> 1, wn = wid & 1;

  const int flat = blockIdx.y * gridDim.x + blockIdx.x;   // 0..7999
  const int swz  = (flat & 7) * 1000 + (flat >> 3);       // bijective (8000%8==0)
  const int bn   = (swz % (VO / 128)) * 128;
  const int bm   = (swz / (VO / 128)) * 128;

  const int r16  = lane & 15, kh = lane >> 4;

  f32x4 acc[4][4];
  #pragma unroll
  for (int i = 0; i < 4; ++i)
    #pragma unroll
    for (int j = 0; j < 4; ++j) acc[i][j] = (f32x4){0.f, 0.f, 0.f, 0.f};

  const int srow = tid >> 3;        // 0..31
  const int scol = (tid & 7) * 8;   // 0..56

  for (int kt = 0; kt < HD / 64; ++kt) {
    __syncthreads();
    #pragma unroll
    for (int p = 0; p < 4; ++p) {
      int row = p * 32 + srow;
      *(bf16x8*)(&As[row][scol]) =
          *(const bf16x8*)(hsb + (size_t)(bm + row) * HD + kt * 64 + scol);
      *(bf16x8*)(&Bs[row][scol]) =
          *(const bf16x8*)(Wb + (size_t)(bn + row) * HD + kt * 64 + scol);
    }
    __syncthreads();
    #pragma unroll
    for (int kk = 0; kk < 2; ++kk) {
      bf16x8 af[4], bfv[4];
      #pragma unroll
      for (int i = 0; i < 4; ++i)
        af[i] = *(const bf16x8*)(&As[64 * wm + 16 * i + r16][kk * 32 + kh * 8]);
      #pragma unroll
      for (int j = 0; j < 4; ++j)
        bfv[j] = *(const bf16x8*)(&Bs[64 * wn + 16 * j + r16][kk * 32 + kh * 8]);
      #pragma unroll
      for (int i = 0; i < 4; ++i)
        #pragma unroll
        for (int j = 0; j < 4; ++j)
          acc[i][j] = __builtin_amdgcn_mfma_f32_16x16x32_bf16(af[i], bfv[j], acc[i][j], 0, 0, 0);
    }
  }

  #pragma unroll
  for (int j = 0; j < 4; ++j) {
    int ncol = bn + 64 * wn + 16 * j + r16;
    float bias = linb[ncol];
    #pragma unroll
    for (int i = 0; i < 4; ++i) {
      int mbase = bm + 64 * wm + 16 * i + kh * 4;
      #pragma unroll
      for (int r = 0; r < 4; ++r) {
        int m = mbase + r;
        int b = m & 63, t = m >> 6;
        out[(size_t)(b * ST + t) * VO + ncol] = acc[i][j][r] + bias;
      }
    }
  }
}

// ---------------- host ----------------

extern "C" void kernel_launch(void* const* d_in, const int* in_sizes, int n_in,
                              void* d_out, int out_size, void* d_ws, size_t ws_size,
                              hipStream_t stream) {
  const int*   toks = (const int*)d_in[0];
  const float* emb  = (const float*)d_in[1];
  const float* eWih = (const float*)d_in[2];
  const float* eWhh = (const float*)d_in[3];
  const float* ebih = (const float*)d_in[4];
  const float* ebhh = (const float*)d_in[5];
  const float* dWih = (const float*)d_in[6];
  const float* dWhh = (const float*)d_in[7];
  const float* dbih = (const float*)d_in[8];
  const float* dbhh = (const float*)d_in[9];
  const float* linW = (const float*)d_in[10];
  const float* linb = (const float*)d_in[11];
  float* out = (float*)d_out;

  char* ws = (char*)d_ws;
  size_t off = 0;
  auto alloc = [&](size_t bytes) {
    void* p = ws + off;
    off = (off + bytes + 255) & ~(size_t)255;
    return p;
  };
  bf16* encX  = (bf16*)alloc((size_t)ST * NBAT * ED * 2);
  bf16* decX  = (bf16*)alloc((size_t)ST * NBAT * ED * 2);
  bf16* WihEb = (bf16*)alloc((size_t)G4 * ED * 2);
  bf16* WhhEb = (bf16*)alloc((size_t)G4 * HD * 2);
  bf16* WihDb = (bf16*)alloc((size_t)G4 * ED * 2);
  bf16* WhhDb = (bf16*)alloc((size_t)G4 * HD * 2);
  bf16* WbL   = (bf16*)alloc((size_t)VO * HD * 2);
  float* bsumE = (float*)alloc(G4 * 4);
  float* bsumD = (float*)alloc(G4 * 4);
  u32*  hx    = (u32*)alloc((size_t)(2 * ST + 1) * SLOT32 * 4);  // 129 x 64 KB
  u32*  hs    = (u32*)alloc((size_t)ST * NBAT * HD * 2);         // [t][b][h]
  int*  len   = (int*)alloc(NBAT * 4);
  u32*  flags = (u32*)alloc(4096);

  // slot 0 (h(0)=0) + flags must be clean every launch
  hipMemsetAsync(hx, 0, (size_t)SLOT32 * 4, stream);
  hipMemsetAsync(flags, 0, 4096, stream);

  k_lengths<<<1, 64, 0, stream>>>(toks, len);
  k_bias<<<(G4 + 255) / 256, 256, 0, stream>>>(ebih, ebhh, bsumE);
  k_bias<<<(G4 + 255) / 256, 256, 0, stream>>>(dbih, dbhh, bsumD);
  k_cast<<<(G4 * ED + 255) / 256, 256, 0, stream>>>(eWih, WihEb, G4 * ED);
  k_cast<<<(G4 * HD + 255) / 256, 256, 0, stream>>>(eWhh, WhhEb, G4 * HD);
  k_cast<<<(G4 * ED + 255) / 256, 256, 0, stream>>>(dWih, WihDb, G4 * ED);
  k_cast<<<(G4 * HD + 255) / 256, 256, 0, stream>>>(dWhh, WhhDb, G4 * HD);
  k_cast<<<(VO * HD + 255) / 256, 256, 0, stream>>>(linW, WbL, VO * HD);
  k_gather<<<(ST * NBAT * ED + 255) / 256, 256, 0, stream>>>(toks, emb, encX, decX);

  k_lstm<<<NWORK, 512, 0, stream>>>(encX, decX, WihEb, WhhEb, WihDb, WhhDb,
                                    bsumE, bsumD, len, hx, hs, flags);

  k_logits<<<dim3(VO / 128, (ST * NBAT) / 128), 256, 0, stream>>>(
      (const bf16*)hs, WbL, linb, out);
}